// Round 13
// baseline (114.363 us; speedup 1.0000x reference)
//
#include <hip/hip_runtime.h>
#include <stdint.h>

// GCN: out[u] = (sum_{(u,v) in E} x[v]) @ W + bias, E sorted by u.
// R12 status: kernel-side ~46us (prep ~9, main ~36) vs fixed harness cost
// ~66us/iter (256MiB ws poison fills dominate the profile). Main's gather
// moves E*256B = 164 MB of 64B lines at ~4.5 TB/s ~= 1 line/8.6cyc/CU —
// consistent with ~64 serviced-lines/CU at ~550cyc latency. R13 is the
// discriminating experiment: 3-deep volley pipeline (24 loads/wave in
// flight, consume waits vmcnt(16)), branchless issue. If flat, the per-CU
// gather service wall is real and this structure is at its floor.

typedef __attribute__((ext_vector_type(8))) short bf16x8;   // 8 bf16 = 4 VGPRs
typedef __attribute__((ext_vector_type(4))) float f32x4;    // MFMA C/D, NT stores

#define WSTRIDE 136   // A-tile k-stride (bf16); row pitch 272B = 17*16B

__device__ __forceinline__ unsigned short f2bf(float f) {
    union { float f; uint32_t u; } c; c.f = f;
    uint32_t u = c.u;
    uint32_t r = (u + 0x7FFFu + ((u >> 16) & 1u)) >> 16;  // RNE
    return (unsigned short)r;
}
__device__ __forceinline__ float bf2f(unsigned short u) {
    union { uint32_t u; float f; } c; c.u = ((uint32_t)u) << 16;
    return c.f;
}

// ---- prep: CSR row_ptr (scatter + parallel tail), W^T bf16, x -> bf16 ----
__global__ __launch_bounds__(256)
void gcn_prep(const float* __restrict__ x, const int* __restrict__ eu,
              const float* __restrict__ W,
              int* __restrict__ row_ptr, unsigned short* __restrict__ Wg,
              unsigned short* __restrict__ xb, int N, int E, int n8)
{
    const int g = blockIdx.x * 256 + threadIdx.x;
    if (g < n8) {                      // cast 8 floats -> 8 bf16 (16B store)
        const float4* x4 = (const float4*)x;
        float4 a = x4[2 * g], b = x4[2 * g + 1];
        union { unsigned short u[8]; uint4 v; } pk;
        pk.u[0] = f2bf(a.x); pk.u[1] = f2bf(a.y); pk.u[2] = f2bf(a.z); pk.u[3] = f2bf(a.w);
        pk.u[4] = f2bf(b.x); pk.u[5] = f2bf(b.y); pk.u[6] = f2bf(b.z); pk.u[7] = f2bf(b.w);
        ((uint4*)xb)[g] = pk.v;
    }
    if (g < E) {                       // interior transitions (bounded gaps)
        int cur  = eu[g];
        int prev = (g > 0) ? eu[g - 1] : -1;
        for (int r = prev + 1; r <= cur; ++r) row_ptr[r] = g;
    }
    if (g <= N) {                      // parallel tail fill (R6 bug fix)
        int last = eu[E - 1];
        if (g > last) row_ptr[g] = E;
    }
    if (g < 16384) {                   // W^T bf16: Wg[n*128+k] = bf16(W[k][n])
        int k = g >> 7, n = g & 127;
        Wg[n * 128 + k] = f2bf(W[g]);
    }
}

__global__ __launch_bounds__(256)
void gcn_main(const unsigned short* __restrict__ xb,   // bf16 x [N][128]
              const int* __restrict__ ev,
              const int* __restrict__ row_ptr,         // [N+1]
              const unsigned short* __restrict__ Wg,   // bf16 W^T [128][128]
              const float* __restrict__ bias,
              float* __restrict__ out,                 // [N][128] f32
              int N, int E)
{
    __shared__ __align__(16) unsigned short At[16 * WSTRIDE];  // block tile [mi][k]

    const int t     = threadIdx.x;
    const int wid   = t >> 6;
    const int lane  = t & 63;
    const int quad  = lane >> 4;
    const int l15   = lane & 15;
    const int eslot = lane >> 4;       // 0..3: edge slot within a gather instr
    const int fo    = l15 * 8;         // 16B chunk of the 256B bf16 row

    const int r0 = blockIdx.x * 16;    // contiguous 16 rows per block

    // ---- 17 boundaries, one coalesced load ----
    int bnd = row_ptr[min(r0 + (lane < 17 ? lane : 16), N)];

    // ---- bias-only fast path (block-uniform; covers the empty ~half) ----
    if (__shfl(bnd, 0) == __shfl(bnd, 16)) {
        const f32x4* b4 = (const f32x4*)bias;
        f32x4*       o4 = (f32x4*)out;
        #pragma unroll
        for (int i = 0; i < 2; ++i) {
            const int f   = i * 256 + t;           // 0..511
            const int row = r0 + (f >> 5);
            if (row < N)
                __builtin_nontemporal_store(b4[f & 31], &o4[(size_t)row * 32 + (f & 31)]);
        }
        return;
    }

    // ---- per-wave: 4 rows, 3-deep volley pipeline (24 loads in flight) ----
    int sA[4], cA[4], vI[4];
    #pragma unroll
    for (int m = 0; m < 4; ++m) {
        sA[m] = __shfl(bnd, wid * 4 + m);
        cA[m] = __shfl(bnd, wid * 4 + m + 1) - sA[m];
    }
    #pragma unroll
    for (int m = 0; m < 4; ++m)        // ALL index loads upfront (4 coalesced)
        vI[m] = ev[min(sA[m] + lane, E - 1)];

    bf16x8 tv[3][8];                   // three volley buffers (32 edges each)

    // branchless issue of rows 0 and 1 (clamped indices always valid)
    #pragma unroll
    for (int k = 0; k < 8; ++k) {
        const int v = __shfl(vI[0], k * 4 + eslot);
        tv[0][k] = *(const bf16x8*)(xb + (size_t)v * 128 + fo);
    }
    #pragma unroll
    for (int k = 0; k < 8; ++k) {
        const int v = __shfl(vI[1], k * 4 + eslot);
        tv[1][k] = *(const bf16x8*)(xb + (size_t)v * 128 + fo);
    }

    #pragma unroll
    for (int m = 0; m < 4; ++m) {
        const int buf = m % 3;
        if (m < 2) {                   // issue row m+2 BEFORE consuming row m
            #pragma unroll
            for (int k = 0; k < 8; ++k) {
                const int v = __shfl(vI[m + 2], k * 4 + eslot);
                tv[(m + 2) % 3][k] = *(const bf16x8*)(xb + (size_t)v * 128 + fo);
            }
        }

        float fa[8];
        #pragma unroll
        for (int i = 0; i < 8; ++i) fa[i] = 0.f;

        #pragma unroll
        for (int k = 0; k < 8; ++k) {              // waits only on tv[buf]
            const float s = (k * 4 + eslot < cA[m]) ? 1.0f : 0.0f;
            #pragma unroll
            for (int i = 0; i < 8; ++i)
                fa[i] = fmaf(bf2f((unsigned short)tv[buf][k][i]), s, fa[i]);
        }
        // rare tail (deg > 32); serial, reuses this row's buffer
        for (int base = 32; base < cA[m]; base += 32) {
            if ((base & 63) == 0)
                vI[m] = ev[min(sA[m] + base + lane, E - 1)];
            #pragma unroll
            for (int k = 0; k < 8; ++k) {
                const int v = __shfl(vI[m], (base + k * 4 + eslot) & 63);
                tv[buf][k] = *(const bf16x8*)(xb + (size_t)v * 128 + fo);
            }
            #pragma unroll
            for (int k = 0; k < 8; ++k) {
                const float s = (base + k * 4 + eslot < cA[m]) ? 1.0f : 0.0f;
                #pragma unroll
                for (int i = 0; i < 8; ++i)
                    fa[i] = fmaf(bf2f((unsigned short)tv[buf][k][i]), s, fa[i]);
            }
        }

        // reduce the 4 edge slots (lanes l15, +16, +32, +48)
        #pragma unroll
        for (int i = 0; i < 8; ++i) {
            fa[i] += __shfl_xor(fa[i], 16);
            fa[i] += __shfl_xor(fa[i], 32);
        }
        if (eslot == 0) {              // lanes 0..15: one 16B store covers the row
            union { unsigned short u[8]; uint4 v; } pk;
            #pragma unroll
            for (int i = 0; i < 8; ++i) pk.u[i] = f2bf(fa[i]);
            *(uint4*)(At + (wid * 4 + m) * WSTRIDE + fo) = pk.v;
        }
    }
    __syncthreads();   // block shares the 16-row tile

    // ---- MFMA: 16 rows x 32 cols per wave ----
    f32x4 acc[2];
    #pragma unroll
    for (int nt = 0; nt < 2; ++nt) { acc[nt].x = 0.f; acc[nt].y = 0.f; acc[nt].z = 0.f; acc[nt].w = 0.f; }

    #pragma unroll
    for (int ks = 0; ks < 4; ++ks) {
        const int kofs = ks * 32 + quad * 8;
        bf16x8 a = *(const bf16x8*)(At + l15 * WSTRIDE + kofs);   // A[mi=l15][k..]
        #pragma unroll
        for (int nt = 0; nt < 2; ++nt) {
            const int col = wid * 32 + nt * 16 + l15;
            bf16x8 b = *(const bf16x8*)(Wg + col * 128 + kofs);   // B^T[n=col][k..]
            acc[nt] = __builtin_amdgcn_mfma_f32_16x16x32_bf16(a, b, acc[nt], 0, 0, 0);
        }
    }

    // ---- Epilogue. C/D: col = lane&15, local row mi = quad*4 + reg ----
    #pragma unroll
    for (int nt = 0; nt < 2; ++nt) {
        const int col = wid * 32 + nt * 16 + l15;
        const float bcol = bias[col];
        #pragma unroll
        for (int r = 0; r < 4; ++r) {
            const int row = r0 + quad * 4 + r;
            if (row < N)
                __builtin_nontemporal_store(acc[nt][r] + bcol,
                                            &out[(long long)row * 128 + col]);
        }
    }
}

extern "C" void kernel_launch(void* const* d_in, const int* in_sizes, int n_in,
                              void* d_out, int out_size, void* d_ws, size_t ws_size,
                              hipStream_t stream) {
    const float* x    = (const float*)d_in[0];
    const int*   ei   = (const int*)d_in[1];     // int32 on device
    const float* W    = (const float*)d_in[2];
    const float* bias = (const float*)d_in[3];
    float*       out  = (float*)d_out;

    const int N = in_sizes[0] / 128;
    const int E = in_sizes[1] / 2;

    const size_t rp_b   = ((size_t)(N + 1) * 4 + 255) & ~(size_t)255;
    const size_t wg_off = rp_b;
    const size_t xb_off = (wg_off + 32768 + 255) & ~(size_t)255;

    int*            row_ptr = (int*)d_ws;
    unsigned short* Wg      = (unsigned short*)((char*)d_ws + wg_off);
    unsigned short* xb      = (unsigned short*)((char*)d_ws + xb_off);

    const int n8 = N * 16;
    int prep_threads = n8 > E ? n8 : E;
    if (prep_threads < N + 1) prep_threads = N + 1;
    gcn_prep<<<(prep_threads + 255) / 256, 256, 0, stream>>>(x, ei, W, row_ptr, Wg, xb, N, E, n8);

    const int grid = (N + 15) / 16;   // contiguous 16 rows/block, 4 per wave
    gcn_main<<<grid, 256, 0, stream>>>(xb, ei + E, row_ptr, Wg, bias, out, N, E);
}